// Round 25
// baseline (236.285 us; speedup 1.0000x reference)
//
#include <hip/hip_runtime.h>
#include <math.h>

#define CH 64
#define S 64
#define S2 (64 * 64)
#define S3 (64 * 64 * 64)

typedef short short8_t __attribute__((ext_vector_type(8)));
typedef float float4_t __attribute__((ext_vector_type(4)));

__device__ __align__(16) unsigned short WB_buf[CH * CH];   // bf16 W[o][c]
__device__ __align__(16) unsigned short peT_buf[32 * 64];  // bf16 peT[t][c], t>=27 zero

__device__ __forceinline__ unsigned short f2bf(float f) {  // RNE to bf16
  unsigned int u = __float_as_uint(f);
  return (unsigned short)((u + 0x7FFFu + ((u >> 16) & 1u)) >> 16);
}

// ---------------------------------------------------------------------------
// Kernel 0: W -> bf16 row-major; pe -> bf16 transposed [t][c] padded to 32 t.
// ---------------------------------------------------------------------------
__global__ __launch_bounds__(256) void wprep(const float* __restrict__ W,
                                             const float* __restrict__ pe) {
  int i = blockIdx.x * 256 + threadIdx.x;  // 0..6143
  if (i < 4096) {
    WB_buf[i] = f2bf(W[i]);
  } else {
    int j = i - 4096;  // 0..2047
    int t = j >> 6, c = j & 63;
    peT_buf[t * 64 + c] = (t < 27) ? f2bf(pe[c * 27 + t]) : (unsigned short)0;
  }
}

// ---------------------------------------------------------------------------
// Fused kernel, float2 / 2-rows-per-wave variant.
// Wave covers rows (d, h0) and (d, h0+1): lane = hoff*32 + wp; positions
// w0=2wp, w1=2wp+1 on row h0+hoff. All gathers are float2 (8B/lane) ->
// total waves HALVE (4096) at the same 10-loads-per-c per-wave structure;
// latency-bound wall ~ (waves/CU)/(resident) rounds: 3.3 -> 2.
// In-pair taps (w0.R, w1.L) are in-register; only 2 cross-lane terms per c.
// Cross-half (lane31/32) shuffle pollution is always masked by wp==0/31.
// pe-MFMA and projection extended to 8 p-tiles (128 positions/wave).
// Plain launch bounds (hints spill, r2-r13); barrier-free per-wave panels
// with compiler fences at cross-lane handoffs (r5/r19-r21 discipline).
// ---------------------------------------------------------------------------
__global__ __launch_bounds__(256) void attn_fused(const float* __restrict__ Q,
                                                  const float* __restrict__ K,
                                                  const float* __restrict__ V,
                                                  const float* __restrict__ bias,
                                                  float* __restrict__ out) {
  __shared__ unsigned short xs[4][128][68];  // 69632 B (time-shared Q/spe/x)
  int tid = threadIdx.x;
  int lane = tid & 63;
  int wv = tid >> 6;
  int wp = lane & 31, hoff = lane >> 5;

  // XCD-aware bijective swizzle (1024 % 8 == 0)
  int raw = blockIdx.x;
  int sw = (raw & 7) * 128 + (raw >> 3);
  int b = sw >> 9;
  int r = sw & 511;
  int d = r >> 3;                                              // 0..63
  int h0 = __builtin_amdgcn_readfirstlane(((r & 7) * 4 + wv) * 2);  // 0..62

  size_t bbase = (size_t)b << 24;
  const float* Qb = Q + bbase;
  const float* Kb = K + bbase;
  const float* Vb = V + bbase;
  float* outb = out + bbase;

  int hl = h0 + hoff;                 // per-lane row
  float lmL0 = (wp == 0) ? 0.f : 1.f;   // w0 left-tap mask
  float lmR1 = (wp == 31) ? 0.f : 1.f;  // w1 right-tap mask

  // per-lane row offsets (clamped) + OOB masks (hoff-dependent -> VGPR)
  int offw[9];
  float okf[9];
#pragma unroll
  for (int dz = 0; dz < 3; ++dz)
#pragma unroll
    for (int dy = 0; dy < 3; ++dy) {
      int rr = dz * 3 + dy;
      int zz = d + dz - 1, yy = hl + dy - 1;
      bool ok = ((unsigned)zz < 64u) & ((unsigned)yy < 64u);
      int zc = zz < 0 ? 0 : (zz > 63 ? 63 : zz);
      int yc = yy < 0 ? 0 : (yy > 63 ? 63 : yy);
      offw[rr] = zc * S2 + yc * S + 2 * wp;
      okf[rr] = ok ? 1.f : 0.f;
    }
  int qoff = d * S2 + hl * S + 2 * wp;  // per-lane own-position offset
  int p0 = hoff * 64 + 2 * wp, p1 = p0 + 1;  // panel rows owned by this lane

  float s0C[9], s0R[9], s1L[9], s1C[9], a0Lp[9], s1Rp[9];
#pragma unroll
  for (int rr = 0; rr < 9; ++rr) {
    s0C[rr] = 0.f; s0R[rr] = 0.f; s1L[rr] = 0.f;
    s1C[rr] = 0.f; a0Lp[rr] = 0.f; s1Rp[rr] = 0.f;
  }

  // ---- Phase A: QK tap scores (float2) + Q->bf16 pack (own rows p0,p1) ----
#pragma unroll 2
  for (int c2 = 0; c2 < CH; c2 += 2) {
    unsigned int qp0 = 0, qp1 = 0;
#pragma unroll
    for (int u = 0; u < 2; ++u) {
      int coff = (c2 + u) * S3;
      float2 qv = *(const float2*)(Qb + coff + qoff);
      float2 kv[9];
#pragma unroll
      for (int rr = 0; rr < 9; ++rr)
        kv[rr] = *(const float2*)(Kb + coff + offw[rr]);
      float q0n = __shfl_down(qv.x, 1);  // lane+1's q0 (producer for w0-left)
      float q1p = __shfl_up(qv.y, 1);    // lane-1's q1 (producer for w1-right)
#pragma unroll
      for (int rr = 0; rr < 9; ++rr) {
        s0C[rr]  = fmaf(qv.x, kv[rr].x, s0C[rr]);   // w0 center
        s0R[rr]  = fmaf(qv.x, kv[rr].y, s0R[rr]);   // w0 right (in-register)
        s1L[rr]  = fmaf(qv.y, kv[rr].x, s1L[rr]);   // w1 left (in-register)
        s1C[rr]  = fmaf(qv.y, kv[rr].y, s1C[rr]);   // w1 center
        a0Lp[rr] = fmaf(q0n,  kv[rr].y, a0Lp[rr]);  // (lane+1 w0)-left, at producer
        s1Rp[rr] = fmaf(q1p,  kv[rr].x, s1Rp[rr]);  // (lane-1 w1)-right, at producer
      }
      qp0 |= ((unsigned int)f2bf(qv.x)) << (16 * u);
      qp1 |= ((unsigned int)f2bf(qv.y)) << (16 * u);
    }
    *(unsigned int*)&xs[wv][p0][c2] = qp0;  // own slots, program-ordered
    *(unsigned int*)&xs[wv][p1][c2] = qp1;
  }

  __asm__ __volatile__("" ::: "memory");
  __threadfence_block();

  // ---- pe-MFMA: spe[t][p] = peT[t][c] * Qbf[c][p] -> LDS float[128][33] ----
  {
    int n16 = lane & 15, g = lane >> 4;
    short8_t pfr[4];  // [mt][kc]
#pragma unroll
    for (int mt = 0; mt < 2; ++mt)
#pragma unroll
      for (int kc = 0; kc < 2; ++kc)
        pfr[mt * 2 + kc] =
            *(const short8_t*)(peT_buf + (mt * 16 + n16) * 64 + kc * 32 + g * 8);
    float* spf = (float*)&xs[wv][0][0];  // view: float[128][33] ([p][t])
#pragma unroll 1
    for (int nt = 0; nt < 8; ++nt) {
      const unsigned short* bp = &xs[wv][nt * 16 + n16][g * 8];
      union { short8_t v; uint2 h[2]; } u0, u1;
      u0.h[0] = *(const uint2*)(bp);
      u0.h[1] = *(const uint2*)(bp + 4);
      u1.h[0] = *(const uint2*)(bp + 32);
      u1.h[1] = *(const uint2*)(bp + 36);
#pragma unroll
      for (int mt = 0; mt < 2; ++mt) {
        float4_t acc = {0.f, 0.f, 0.f, 0.f};
        acc = __builtin_amdgcn_mfma_f32_16x16x32_bf16(pfr[mt * 2],     u0.v, acc, 0, 0, 0);
        acc = __builtin_amdgcn_mfma_f32_16x16x32_bf16(pfr[mt * 2 + 1], u1.v, acc, 0, 0, 0);
        // nt's float-row writes end before nt+1's ushort B-frag reads begin
#pragma unroll
        for (int j = 0; j < 4; ++j)
          spf[(nt * 16 + n16) * 33 + mt * 16 + g * 4 + j] = acc[j];
      }
    }
  }

  __asm__ __volatile__("" ::: "memory");
  __threadfence_block();

  // ---- assemble 2x27 tap scores; pe part read straight from LDS ----
  float s0[27], s1[27];
  {
    const float* spf = (const float*)&xs[wv][0][0];
    int b0 = p0 * 33, b1 = p1 * 33;
#pragma unroll
    for (int rr = 0; rr < 9; ++rr) {
      float l0 = __shfl_up(a0Lp[rr], 1) * lmL0;    // w0 left (masked cross-half)
      float r1 = __shfl_down(s1Rp[rr], 1) * lmR1;  // w1 right (masked cross-half)
      s0[rr * 3]     = fmaf(l0,      okf[rr], spf[b0 + rr * 3]);
      s0[rr * 3 + 1] = fmaf(s0C[rr], okf[rr], spf[b0 + rr * 3 + 1]);
      s0[rr * 3 + 2] = fmaf(s0R[rr], okf[rr], spf[b0 + rr * 3 + 2]);
      s1[rr * 3]     = fmaf(s1L[rr], okf[rr], spf[b1 + rr * 3]);
      s1[rr * 3 + 1] = fmaf(s1C[rr], okf[rr], spf[b1 + rr * 3 + 1]);
      s1[rr * 3 + 2] = fmaf(r1,      okf[rr], spf[b1 + rr * 3 + 2]);
    }
  }

  // ---- two softmaxes (base-2; normalization folded into weights) ----
  const float SC = 0.125f * 1.44269504088896f;
#pragma unroll
  for (int t = 0; t < 27; ++t) { s0[t] *= SC; s1[t] *= SC; }
  float m0 = s0[0], m1 = s1[0];
#pragma unroll
  for (int t = 1; t < 27; ++t) { m0 = fmaxf(m0, s0[t]); m1 = fmaxf(m1, s1[t]); }
  float sum0 = 0.f, sum1 = 0.f;
#pragma unroll
  for (int t = 0; t < 27; ++t) {
    s0[t] = exp2f(s0[t] - m0); sum0 += s0[t];
    s1[t] = exp2f(s1[t] - m1); sum1 += s1[t];
  }
  float inv0 = 1.f / sum0, inv1 = 1.f / sum1;

  // ---- weights (fold inv + row mask); pre-shuffle cross weights ----
  float wC0[9], wR0[9], wL1[9], wC1[9], sL0s[9], sR1s[9];
#pragma unroll
  for (int rr = 0; rr < 9; ++rr) {
    float f0 = inv0 * okf[rr], f1 = inv1 * okf[rr];
    wC0[rr] = s0[rr * 3 + 1] * f0;
    wR0[rr] = s0[rr * 3 + 2] * f0;
    wL1[rr] = s1[rr * 3] * f1;
    wC1[rr] = s1[rr * 3 + 1] * f1;
    sL0s[rr] = __shfl_down(s0[rr * 3] * f0, 1);      // w0-left wt at producer
    sR1s[rr] = __shfl_up(s1[rr * 3 + 2] * f1, 1);    // w1-right wt at producer
  }

  __asm__ __volatile__("" ::: "memory");
  __threadfence_block();

  // ---- Phase B: float2 V-gather -> x bf16 -> own panel rows p0,p1 ----
#pragma unroll 2
  for (int c2 = 0; c2 < CH; c2 += 2) {
    unsigned int xp0 = 0, xp1 = 0;
#pragma unroll
    for (int u = 0; u < 2; ++u) {
      int coff = (c2 + u) * S3;
      float2 vv[9];
#pragma unroll
      for (int rr = 0; rr < 9; ++rr)
        vv[rr] = *(const float2*)(Vb + coff + offw[rr]);
      float own0 = 0.f, own1 = 0.f, cX0 = 0.f, cX1 = 0.f;
#pragma unroll
      for (int rr = 0; rr < 9; ++rr) {
        own0 = fmaf(wC0[rr], vv[rr].x, own0);
        own0 = fmaf(wR0[rr], vv[rr].y, own0);
        own1 = fmaf(wL1[rr], vv[rr].x, own1);
        own1 = fmaf(wC1[rr], vv[rr].y, own1);
        cX0  = fmaf(sL0s[rr], vv[rr].y, cX0);  // for lane+1's w0-left
        cX1  = fmaf(sR1s[rr], vv[rr].x, cX1);  // for lane-1's w1-right
      }
      float x0 = own0 + __shfl_up(cX0, 1) * lmL0;
      float x1 = own1 + __shfl_down(cX1, 1) * lmR1;
      xp0 |= ((unsigned int)f2bf(x0)) << (16 * u);
      xp1 |= ((unsigned int)f2bf(x1)) << (16 * u);
    }
    *(unsigned int*)&xs[wv][p0][c2] = xp0;
    *(unsigned int*)&xs[wv][p1][c2] = xp1;
  }

  __asm__ __volatile__("" ::: "memory");
  __threadfence_block();

  // ---- Phase P: MFMA projection over 8 p-tiles, ot-outer/pt-inner ----
  {
    int n16 = lane & 15, g = lane >> 4;
    int upos0 = d * S2 + h0 * S;
#pragma unroll 1
    for (int ot = 0; ot < 4; ++ot) {
      short8_t a0 = *(const short8_t*)(WB_buf + (ot * 16 + n16) * CH + g * 8);
      short8_t a1 = *(const short8_t*)(WB_buf + (ot * 16 + n16) * CH + 32 + g * 8);
      int obase = ot * 16 + 4 * g;
      float4_t bv = *(const float4_t*)(bias + obase);
#pragma unroll 1
      for (int pt = 0; pt < 8; ++pt) {
        const unsigned short* bp = &xs[wv][pt * 16 + n16][g * 8];
        union { short8_t v; uint2 h[2]; } u0, u1;
        u0.h[0] = *(const uint2*)(bp);
        u0.h[1] = *(const uint2*)(bp + 4);
        u1.h[0] = *(const uint2*)(bp + 32);
        u1.h[1] = *(const uint2*)(bp + 36);
        float4_t acc = {0.f, 0.f, 0.f, 0.f};
        acc = __builtin_amdgcn_mfma_f32_16x16x32_bf16(a0, u0.v, acc, 0, 0, 0);
        acc = __builtin_amdgcn_mfma_f32_16x16x32_bf16(a1, u1.v, acc, 0, 0, 0);
        int pidx = upos0 + (pt >> 2) * S + (pt & 3) * 16 + n16;
#pragma unroll
        for (int j = 0; j < 4; ++j)
          outb[(obase + j) * S3 + pidx] = acc[j] + bv[j];
      }
    }
  }
}

// ---------------------------------------------------------------------------
extern "C" void kernel_launch(void* const* d_in, const int* in_sizes, int n_in,
                              void* d_out, int out_size, void* d_ws, size_t ws_size,
                              hipStream_t stream) {
  const float* Q = (const float*)d_in[0];
  const float* K = (const float*)d_in[1];
  const float* V = (const float*)d_in[2];
  const float* pe = (const float*)d_in[3];
  const float* W = (const float*)d_in[4];
  const float* bias = (const float*)d_in[5];
  float* out = (float*)d_out;

  wprep<<<24, 256, 0, stream>>>(W, pe);
  attn_fused<<<1024, 256, 0, stream>>>(Q, K, V, bias, out);
}

// Round 26
// 203.931 us; speedup vs baseline: 1.1587x; 1.1587x over previous
//
#include <hip/hip_runtime.h>
#include <math.h>

#define CH 64
#define S 64
#define S2 (64 * 64)
#define S3 (64 * 64 * 64)

typedef short short8_t __attribute__((ext_vector_type(8)));
typedef float float4_t __attribute__((ext_vector_type(4)));

__device__ __align__(16) unsigned short WB_buf[CH * CH];   // bf16 W[o][c]
__device__ __align__(16) unsigned short peT_buf[32 * 64];  // bf16 peT[t][c], t>=27 zero

__device__ __forceinline__ unsigned short f2bf(float f) {  // RNE to bf16
  unsigned int u = __float_as_uint(f);
  return (unsigned short)((u + 0x7FFFu + ((u >> 16) & 1u)) >> 16);
}

// ---------------------------------------------------------------------------
// Kernel 0: W -> bf16 row-major; pe -> bf16 transposed [t][c] padded to 32 t.
// ---------------------------------------------------------------------------
__global__ __launch_bounds__(256) void wprep(const float* __restrict__ W,
                                             const float* __restrict__ pe) {
  int i = blockIdx.x * 256 + threadIdx.x;  // 0..6143
  if (i < 4096) {
    WB_buf[i] = f2bf(W[i]);
  } else {
    int j = i - 4096;  // 0..2047
    int t = j >> 6, c = j & 63;
    peT_buf[t * 64 + c] = (t < 27) ? f2bf(pe[c * 27 + t]) : (unsigned short)0;
  }
}

// ---------------------------------------------------------------------------
// Fused kernel — measured optimum (r21/r24, 203 us total, reproduced twice).
// Phase A: QK tap scores (27 accs) + Q->bf16 pack into per-wave LDS panel.
// pe-MFMA: spe = peT x Q (16 mfma), C-frags redistributed via LDS float view.
// assemble -> softmax -> weights -> Phase B: V-gather -> x bf16 panel.
// Phase P: out = W x (32 mfma, ot-outer/pt-inner minimal live frags) + bias.
// Plain launch bounds (min-waves hints spill: r2-r13). Barrier-free: panels
// are per-wave; same-wave DS is HW-in-order; compiler fenced at handoffs.
// Latency-bound at ~2.5 waves/SIMD (unified-regfile cap ~150 regs). All
// lever families A/B-tested and exhausted (r16-r25): occupancy shaping,
// source-MLP, LDS-DMA pipelining, workgroup shaping, fusion topology,
// thread coarsening. Practical floor at HIP source level.
// ---------------------------------------------------------------------------
__global__ __launch_bounds__(256) void attn_fused(const float* __restrict__ Q,
                                                  const float* __restrict__ K,
                                                  const float* __restrict__ V,
                                                  const float* __restrict__ bias,
                                                  float* __restrict__ out) {
  __shared__ unsigned short xs[4][CH][68];  // 34816 B (time-shared: Q/spe/x)
  int tid = threadIdx.x;
  int lane = tid & 63;
  int wv = tid >> 6;

  // XCD-aware bijective swizzle (2048 % 8 == 0)
  int raw = blockIdx.x;
  int sw = (raw & 7) * 256 + (raw >> 3);
  int b = sw >> 10;
  int r = sw & 1023;
  int d = r >> 4;                                             // 0..63
  int hu = __builtin_amdgcn_readfirstlane((r & 15) * 4 + wv);  // 0..63, uniform

  size_t bbase = (size_t)b << 24;
  const float* Qb = Q + bbase;
  const float* Kb = K + bbase;
  const float* Vb = V + bbase;
  float* outb = out + bbase;

  float lmL = (lane == 0) ? 0.f : 1.f;
  float lmR = (lane == 63) ? 0.f : 1.f;

  // uniform row offsets (clamped) + OOB masks; K pointers now, V later
  int rowoff[9];
  float okf[9];
  const float* krow[9];
#pragma unroll
  for (int dz = 0; dz < 3; ++dz)
#pragma unroll
    for (int dy = 0; dy < 3; ++dy) {
      int rr = dz * 3 + dy;
      int zz = d + dz - 1, yy = hu + dy - 1;
      bool ok = ((unsigned)zz < 64u) & ((unsigned)yy < 64u);
      int zc = zz < 0 ? 0 : (zz > 63 ? 63 : zz);
      int yc = yy < 0 ? 0 : (yy > 63 ? 63 : yy);
      rowoff[rr] = __builtin_amdgcn_readfirstlane(zc * S2 + yc * S);
      krow[rr] = Kb + rowoff[rr];
      okf[rr] = ok ? 1.f : 0.f;
    }
  int upos = d * S2 + hu * S;
  int pos = upos + lane;

  float sC[9], sXR[9], sXL[9];
#pragma unroll
  for (int rr = 0; rr < 9; ++rr) { sC[rr] = 0.f; sXR[rr] = 0.f; sXL[rr] = 0.f; }

  // ---- Phase A: QK tap scores + Q->bf16 LDS pack (own row [lane][c]) ----
#pragma unroll 2
  for (int c2 = 0; c2 < CH; c2 += 2) {
    unsigned int qpack = 0;
#pragma unroll
    for (int u = 0; u < 2; ++u) {
      int coff = (c2 + u) * S3;
      float q = Qb[coff + pos];
      float rv[9];
#pragma unroll
      for (int rr = 0; rr < 9; ++rr) rv[rr] = krow[rr][coff + lane];
      float qR = __shfl_down(q, 1);
      float qL = __shfl_up(q, 1);
#pragma unroll
      for (int rr = 0; rr < 9; ++rr) {
        sC[rr]  = fmaf(q,  rv[rr], sC[rr]);
        sXR[rr] = fmaf(qR, rv[rr], sXR[rr]);  // lane+1's left tap
        sXL[rr] = fmaf(qL, rv[rr], sXL[rr]);  // lane-1's right tap
      }
      qpack |= ((unsigned int)f2bf(q)) << (16 * u);
    }
    *(unsigned int*)&xs[wv][lane][c2] = qpack;  // own slot, program-ordered
  }

  __asm__ __volatile__("" ::: "memory");
  __threadfence_block();

  // ---- pe-MFMA: spe[t][p] = peT[t][c] * Qbf[c][p] -> LDS float[64][33] ----
  {
    int n16 = lane & 15, g = lane >> 4;
    short8_t pfr[4];  // [mt][kc]
#pragma unroll
    for (int mt = 0; mt < 2; ++mt)
#pragma unroll
      for (int kc = 0; kc < 2; ++kc)
        pfr[mt * 2 + kc] =
            *(const short8_t*)(peT_buf + (mt * 16 + n16) * 64 + kc * 32 + g * 8);
    float* spf = (float*)&xs[wv][0][0];  // view: float[64][33] ([p][t])
#pragma unroll 1
    for (int nt = 0; nt < 4; ++nt) {
      const unsigned short* bp = &xs[wv][nt * 16 + n16][g * 8];
      union { short8_t v; uint2 h[2]; } u0, u1;
      u0.h[0] = *(const uint2*)(bp);
      u0.h[1] = *(const uint2*)(bp + 4);
      u1.h[0] = *(const uint2*)(bp + 32);
      u1.h[1] = *(const uint2*)(bp + 36);
#pragma unroll
      for (int mt = 0; mt < 2; ++mt) {
        float4_t acc = {0.f, 0.f, 0.f, 0.f};
        acc = __builtin_amdgcn_mfma_f32_16x16x32_bf16(pfr[mt * 2],     u0.v, acc, 0, 0, 0);
        acc = __builtin_amdgcn_mfma_f32_16x16x32_bf16(pfr[mt * 2 + 1], u1.v, acc, 0, 0, 0);
        // D: col(p)=n16, row(t)=mt*16+g*4+j -> write [p][t] rows this nt owns
#pragma unroll
        for (int j = 0; j < 4; ++j)
          spf[(nt * 16 + n16) * 33 + mt * 16 + g * 4 + j] = acc[j];
      }
    }
  }

  __asm__ __volatile__("" ::: "memory");
  __threadfence_block();

  // ---- assemble 27 tap scores; pe part read straight from LDS ----
  float s[27];
  {
    const float* spf = (const float*)&xs[wv][0][0];
    int sbase = lane * 33;
#pragma unroll
    for (int rr = 0; rr < 9; ++rr) {
      float lt = __shfl_up(sXR[rr], 1);
      float rt = __shfl_down(sXL[rr], 1);
      s[rr * 3]     = fmaf(lt * lmL, okf[rr], spf[sbase + rr * 3]);
      s[rr * 3 + 1] = fmaf(sC[rr],   okf[rr], spf[sbase + rr * 3 + 1]);
      s[rr * 3 + 2] = fmaf(rt * lmR, okf[rr], spf[sbase + rr * 3 + 2]);
    }
  }

  // ---- softmax (base-2; normalization folded into weights) ----
  const float SC = 0.125f * 1.44269504088896f;
#pragma unroll
  for (int t = 0; t < 27; ++t) s[t] *= SC;
  float m = s[0];
#pragma unroll
  for (int t = 1; t < 27; ++t) m = fmaxf(m, s[t]);
  float sum = 0.f;
#pragma unroll
  for (int t = 0; t < 27; ++t) {
    s[t] = exp2f(s[t] - m);
    sum += s[t];
  }
  float inv = 1.f / sum;

  // ---- weights + V row pointers (deferred live range) ----
  float wC[9], sLs[9], sRs[9];
  const float* vrow[9];
#pragma unroll
  for (int rr = 0; rr < 9; ++rr) {
    vrow[rr] = Vb + rowoff[rr];
    float f = inv * okf[rr];
    float wL = s[rr * 3] * f;
    wC[rr]   = s[rr * 3 + 1] * f;
    float wR = s[rr * 3 + 2] * f;
    sLs[rr] = __shfl_down(wL, 1);
    sRs[rr] = __shfl_up(wR, 1);
  }

  __asm__ __volatile__("" ::: "memory");
  __threadfence_block();

  // ---- Phase B: V-gather -> x bf16 pairs -> own LDS row [lane][c] ----
#pragma unroll 2
  for (int c2 = 0; c2 < CH; c2 += 2) {
    unsigned int packed = 0;
#pragma unroll
    for (int u = 0; u < 2; ++u) {
      int coff = (c2 + u) * S3;
      float rv[9];
#pragma unroll
      for (int rr = 0; rr < 9; ++rr) rv[rr] = vrow[rr][coff + lane];
      float own = 0.f, cR = 0.f, cL = 0.f;
#pragma unroll
      for (int rr = 0; rr < 9; ++rr) {
        own = fmaf(wC[rr], rv[rr], own);
        cR  = fmaf(sLs[rr], rv[rr], cR);
        cL  = fmaf(sRs[rr], rv[rr], cL);
      }
      float x_c = own + __shfl_up(cR, 1) * lmL + __shfl_down(cL, 1) * lmR;
      packed |= ((unsigned int)f2bf(x_c)) << (16 * u);
    }
    *(unsigned int*)&xs[wv][lane][c2] = packed;
  }

  __asm__ __volatile__("" ::: "memory");
  __threadfence_block();

  // ---- Phase P: MFMA projection, ot-outer/pt-inner, minimal live frags ----
  {
    int n16 = lane & 15, g = lane >> 4;
#pragma unroll 1
    for (int ot = 0; ot < 4; ++ot) {
      short8_t a0 = *(const short8_t*)(WB_buf + (ot * 16 + n16) * CH + g * 8);
      short8_t a1 = *(const short8_t*)(WB_buf + (ot * 16 + n16) * CH + 32 + g * 8);
      int obase = ot * 16 + 4 * g;
      float4_t bv = *(const float4_t*)(bias + obase);
#pragma unroll 1
      for (int pt = 0; pt < 4; ++pt) {
        const unsigned short* bp = &xs[wv][pt * 16 + n16][g * 8];
        union { short8_t v; uint2 h[2]; } u0, u1;
        u0.h[0] = *(const uint2*)(bp);
        u0.h[1] = *(const uint2*)(bp + 4);
        u1.h[0] = *(const uint2*)(bp + 32);
        u1.h[1] = *(const uint2*)(bp + 36);
        float4_t acc = {0.f, 0.f, 0.f, 0.f};
        acc = __builtin_amdgcn_mfma_f32_16x16x32_bf16(a0, u0.v, acc, 0, 0, 0);
        acc = __builtin_amdgcn_mfma_f32_16x16x32_bf16(a1, u1.v, acc, 0, 0, 0);
#pragma unroll
        for (int j = 0; j < 4; ++j)
          outb[(obase + j) * S3 + upos + pt * 16 + n16] = acc[j] + bv[j];
      }
    }
  }
}

// ---------------------------------------------------------------------------
extern "C" void kernel_launch(void* const* d_in, const int* in_sizes, int n_in,
                              void* d_out, int out_size, void* d_ws, size_t ws_size,
                              hipStream_t stream) {
  const float* Q = (const float*)d_in[0];
  const float* K = (const float*)d_in[1];
  const float* V = (const float*)d_in[2];
  const float* pe = (const float*)d_in[3];
  const float* W = (const float*)d_in[4];
  const float* bias = (const float*)d_in[5];
  float* out = (float*)d_out;

  wprep<<<24, 256, 0, stream>>>(W, pe);
  attn_fused<<<2048, 256, 0, stream>>>(Q, K, V, bias, out);
}